// Round 2
// 4491.185 us; speedup vs baseline: 1.3707x; 1.3707x over previous
//
#include <hip/hip_runtime.h>
#include <math.h>

// ---------------------------------------------------------------------------
// FNO-GRU 2D: B=16, SX=SY=64, W=64 channels, T=20 steps, YH=33, NFREQ=2112.
// Weights stay in natural [i][o][f] layout (f fastest).
// Workspace (~69 MB):
//   h  : [b][c][x][y] float, 4,194,304
//   B0/B1/B2 : spectral float2 buffers, 2,162,688 each, image-major [img][f].
// Dispatches/step: pw2, fifft_r, pw1, fifft_n, yproj.
//
// Round-5: pw2/pw1 rocprof showed 1.08 TB/s HBM (13.5%), VALUBusy 23%,
// occupancy 17.6% -> bound by L1 load-return bandwidth (weight lines loaded
// 4x per block, Hf lines 8x; 2.16 GB of load returns for 172 MB unique)
// plus exposed miss latency. Rewritten as 2-phase LDS-staged pipeline:
// per KI=2 i-step, stage 8 KB weights + 4 KB Hf into LDS with
// global_load_lds (width 16, double-buffered); all 4 waves read operands
// from LDS. Global traffic per block-iter drops 32 KB -> 6 KB.
// Round-6: round-5 bench died in container bring-up (infra, no stages ran).
// Re-audited staging maps (bounds/alignment/barrier uniformity) - clean.
// Resubmitting unchanged.
//
// NOTE (round-4 post-mortem, still applies): manual software-pipeline VGPR
// arrays spilled (256 VGPR, 1.1 GB scratch writes). Keep accumulators at
// 32 floats and let LDS double-buffering do the pipelining.
// ---------------------------------------------------------------------------

#define NIMG   1024         // B*W images
#define NFREQ  2112         // 64*33
#define IMGSZ  4096         // 64*64
#define INV_N  (1.0f/4096.0f)

constexpr int brev6(int i) {
    int r = 0;
    for (int b = 0; b < 6; ++b) r |= ((i >> b) & 1) << (5 - b);
    return r;
}

// 64-point complex FFT, fully unrolled radix-2 DIT. DSIGN=-1 fwd, +1 inv.
template <int DSIGN>
__device__ __forceinline__ void fft64(float* xr, float* xi,
                                      const float* cs, const float* sn) {
#pragma unroll
    for (int i = 0; i < 64; ++i) {
        const int j = brev6(i);
        if (j > i) {
            float tr = xr[i]; xr[i] = xr[j]; xr[j] = tr;
            float ti = xi[i]; xi[i] = xi[j]; xi[j] = ti;
        }
    }
#pragma unroll
    for (int s = 1; s <= 6; ++s) {
        const int m = 1 << s, h = m >> 1, step = 64 >> s;
#pragma unroll
        for (int j = 0; j < h; ++j) {
            const int tw = j * step;
            float c = 1.0f, sg = 0.0f;
            if (tw != 0) {
                c  = cs[tw];
                sg = (DSIGN < 0) ? -sn[tw] : sn[tw];
            }
#pragma unroll
            for (int k = j; k < 64; k += m) {
                const int p = k, q = k + h;
                const float vr = xr[q], vi = xi[q];
                float tr, ti;
                if (tw == 0) { tr = vr; ti = vi; }
                else         { tr = c * vr - sg * vi; ti = c * vi + sg * vr; }
                const float ur = xr[p], ui = xi[p];
                xr[p] = ur + tr; xi[p] = ui + ti;
                xr[q] = ur - tr; xi[q] = ui - ti;
            }
        }
    }
}

__device__ __forceinline__ void init_twiddles(float* cs, float* sn, int t) {
    float s, c;
    sincosf(6.28318530717958647692f * (float)t * (1.0f / 64.0f), &s, &c);
    cs[t] = c; sn[t] = s;
}

__device__ __forceinline__ float sigmoidf_(float v) {
    return 1.0f / (1.0f + expf(-v));
}

// ---- shared FFT pass helpers (lds: float2[64*33], row-major [x][k]) -------
__device__ __forceinline__ void ifft_pass_x(const float2* __restrict__ F,
                                            float2* lds, const float* cs,
                                            const float* sn, int t) {
    __syncthreads();
    if (t < 33) {
        float ar[64], ai[64];
#pragma unroll
        for (int kx = 0; kx < 64; ++kx) {
            float2 v = F[kx * 33 + t];
            ar[kx] = v.x; ai[kx] = v.y;
        }
        fft64<1>(ar, ai, cs, sn);
#pragma unroll
        for (int x = 0; x < 64; ++x) lds[x * 33 + t] = make_float2(ar[x], ai[x]);
    }
    __syncthreads();
}

__device__ __forceinline__ void ifft_pass_y(const float2* lds, float* xr,
                                            float* xi, const float* cs,
                                            const float* sn, int t) {
#pragma unroll
    for (int k = 0; k <= 32; ++k) {
        float2 v = lds[t * 33 + k];
        xr[k] = v.x; xi[k] = v.y;
    }
#pragma unroll
    for (int k = 33; k < 64; ++k) {
        float2 v = lds[t * 33 + (64 - k)];
        xr[k] = v.x; xi[k] = -v.y;
    }
    fft64<1>(xr, xi, cs, sn);
}

__device__ __forceinline__ void fwd_pass_y(float* xr, float* xi, float2* lds,
                                           const float* cs, const float* sn,
                                           int t) {
    fft64<-1>(xr, xi, cs, sn);
#pragma unroll
    for (int k = 0; k <= 32; ++k) lds[t * 33 + k] = make_float2(xr[k], xi[k]);
}

__device__ __forceinline__ void fwd_pass_x(const float2* lds,
                                           float2* __restrict__ out,
                                           const float* cs, const float* sn,
                                           int t) {
    __syncthreads();
    if (t < 33) {
        float ar[64], ai[64];
#pragma unroll
        for (int x = 0; x < 64; ++x) {
            float2 v = lds[x * 33 + t];
            ar[x] = v.x; ai[x] = v.y;
        }
        fft64<-1>(ar, ai, cs, sn);
#pragma unroll
        for (int kx = 0; kx < 64; ++kx) out[kx * 33 + t] = make_float2(ar[kx], ai[kx]);
    }
}

// ---------------- h0 = x*Wi[c]+bi[c], then rfft2 -> Hf ---------------------
__global__ __launch_bounds__(64) void k_h0fft(const float* __restrict__ x,
                                              const float* __restrict__ Wi,
                                              const float* __restrict__ bi,
                                              float* __restrict__ h,
                                              float2* __restrict__ Hf) {
    __shared__ float cs[64], sn[64];
    __shared__ float2 lds[64 * 33];
    const int t = threadIdx.x;
    init_twiddles(cs, sn, t);
    __syncthreads();
    const int ib = blockIdx.x;        // b*64+c
    const int c = ib & 63, b = ib >> 6;
    const float wi = Wi[c], bc = bi[c];

    float xr[64], xi[64];
    const float4* xrow = (const float4*)(x + (size_t)b * IMGSZ + t * 64);
    float4* hrow = (float4*)(h + (size_t)ib * IMGSZ + t * 64);
#pragma unroll
    for (int k = 0; k < 16; ++k) {
        float4 v = xrow[k];
        v.x = v.x * wi + bc; v.y = v.y * wi + bc;
        v.z = v.z * wi + bc; v.w = v.w * wi + bc;
        hrow[k] = v;
        xr[4 * k + 0] = v.x; xr[4 * k + 1] = v.y;
        xr[4 * k + 2] = v.z; xr[4 * k + 3] = v.w;
    }
#pragma unroll
    for (int k = 0; k < 64; ++k) xi[k] = 0.0f;
    fwd_pass_y(xr, xi, lds, cs, sn, t);
    fwd_pass_x(lds, Hf + (size_t)ib * NFREQ, cs, sn, t);
}

// ---------------- irfft2(Rf) -> r; rh = sigmoid(r)*h; rfft2(rh) -> RHf -----
__global__ __launch_bounds__(64) void k_fifft_r(const float2* __restrict__ Rf,
                                                const float* __restrict__ h,
                                                float2* __restrict__ RHf) {
    __shared__ float cs[64], sn[64];
    __shared__ float2 lds[64 * 33];
    const int t = threadIdx.x;
    init_twiddles(cs, sn, t);
    const size_t ib = blockIdx.x;
    float xr[64], xi[64];

    ifft_pass_x(Rf + ib * NFREQ, lds, cs, sn, t);
    ifft_pass_y(lds, xr, xi, cs, sn, t);
    const float4* h4 = (const float4*)(h + ib * IMGSZ + t * 64);
#pragma unroll
    for (int k = 0; k < 16; ++k) {
        float4 hv = h4[k];
        xr[4 * k + 0] = sigmoidf_(xr[4 * k + 0] * INV_N) * hv.x;
        xr[4 * k + 1] = sigmoidf_(xr[4 * k + 1] * INV_N) * hv.y;
        xr[4 * k + 2] = sigmoidf_(xr[4 * k + 2] * INV_N) * hv.z;
        xr[4 * k + 3] = sigmoidf_(xr[4 * k + 3] * INV_N) * hv.w;
    }
#pragma unroll
    for (int k = 0; k < 64; ++k) xi[k] = 0.0f;
    fwd_pass_y(xr, xi, lds, cs, sn, t);
    fwd_pass_x(lds, RHf + ib * NFREQ, cs, sn, t);
}

// ---- irfft2(Zf)->z, irfft2(Nf)->n, h=(1-z)h+z*tanh(n); write h + rfft2(h) -
__global__ __launch_bounds__(64) void k_fifft_n(const float2* __restrict__ Nf,
                                                const float2* __restrict__ Zf,
                                                float* __restrict__ h,
                                                float2* __restrict__ Hfn) {
    __shared__ float cs[64], sn[64];
    __shared__ float2 lds[64 * 33];
    __shared__ float zbuf[64 * 64];
    const int t = threadIdx.x;
    init_twiddles(cs, sn, t);
    const size_t ib = blockIdx.x;
    float xr[64], xi[64];

    ifft_pass_x(Zf + ib * NFREQ, lds, cs, sn, t);
    ifft_pass_y(lds, xr, xi, cs, sn, t);
#pragma unroll
    for (int k = 0; k < 64; ++k) zbuf[t * 64 + k] = sigmoidf_(xr[k] * INV_N);

    ifft_pass_x(Nf + ib * NFREQ, lds, cs, sn, t);
    ifft_pass_y(lds, xr, xi, cs, sn, t);
    float4* h4 = (float4*)(h + ib * IMGSZ + t * 64);
    const float4* z4 = (const float4*)(zbuf + t * 64);
#pragma unroll
    for (int k = 0; k < 16; ++k) {
        float4 hv = h4[k];
        float4 zv = z4[k];
        hv.x = (1.0f - zv.x) * hv.x + zv.x * tanhf(xr[4 * k + 0] * INV_N);
        hv.y = (1.0f - zv.y) * hv.y + zv.y * tanhf(xr[4 * k + 1] * INV_N);
        hv.z = (1.0f - zv.z) * hv.z + zv.z * tanhf(xr[4 * k + 2] * INV_N);
        hv.w = (1.0f - zv.w) * hv.w + zv.w * tanhf(xr[4 * k + 3] * INV_N);
        h4[k] = hv;
        xr[4 * k + 0] = hv.x; xr[4 * k + 1] = hv.y;
        xr[4 * k + 2] = hv.z; xr[4 * k + 3] = hv.w;
    }
#pragma unroll
    for (int k = 0; k < 64; ++k) xi[k] = 0.0f;
    fwd_pass_y(xr, xi, lds, cs, sn, t);
    fwd_pass_x(lds, Hfn + ib * NFREQ, cs, sn, t);
}

// ---------------- pointwise complex channel mix ----------------------------
// O[b][o][f] = sum_i H[b][i][f] * w[i][o][f]   (complex)
// grid (66, 8, 2): x = 32-complex-freq tile, y = 8-o group, z = 8-b group.
// thread t: fq = t&7 (4 cf each), og = (t>>3)&7 (o in group), w = t>>6
// (wave = b-pair). 2-phase LDS pipeline, KI=2 i's per stage step:
//   Wl[buf][ki][arr][o*8+fq]  (float4, weights)  -- wave w stages arr=w
//   Hl[buf][ki][b_loc][slot]  (float4 = 2 cf)    -- wave w stages ki=w>>1,
//                                                   b_loc (w&1)*4..+3
// global_load_lds writes wave-uniform base + lane*16; lane l = (o_l*8+fq_l)
// for weights and (b_off*16+slot) for Hf, matching the layouts above.
__device__ __forceinline__ void gld_lds16(const void* g, void* l) {
    __builtin_amdgcn_global_load_lds(
        (const __attribute__((address_space(1))) unsigned int*)g,
        (__attribute__((address_space(3))) unsigned int*)l, 16, 0, 0);
}

__device__ __forceinline__ void cmadd4(float (&are)[4], float (&aim)[4],
                                       const float4 hA, const float4 hB,
                                       const float4 wr, const float4 wi) {
    are[0] += hA.x * wr.x - hA.y * wi.x;  aim[0] += hA.x * wi.x + hA.y * wr.x;
    are[1] += hA.z * wr.y - hA.w * wi.y;  aim[1] += hA.z * wi.y + hA.w * wr.y;
    are[2] += hB.x * wr.z - hB.y * wi.z;  aim[2] += hB.x * wi.z + hB.y * wr.z;
    are[3] += hB.z * wr.w - hB.w * wi.w;  aim[3] += hB.z * wi.w + hB.w * wr.w;
}

__global__ __launch_bounds__(256) void k_pw2(const float2* __restrict__ Hf,
                                             const float* __restrict__ wzr,
                                             const float* __restrict__ wzi,
                                             const float* __restrict__ wrr,
                                             const float* __restrict__ wri,
                                             float2* __restrict__ Zf,
                                             float2* __restrict__ Rf) {
    __shared__ float4 Wl[2][2][4][64];   // 16 KB
    __shared__ float4 Hl[2][2][8][16];   //  8 KB
    const int t  = threadIdx.x;
    const int l  = t & 63, w = t >> 6;       // lane, wave
    const int fq = t & 7,  og = (t >> 3) & 7;
    const int o  = blockIdx.y * 8 + og;
    const int b0 = blockIdx.z * 8 + w * 2;
    const int fA = blockIdx.x * 32 + fq * 4;
    const size_t wstep = (size_t)64 * NFREQ;

    // staging source bases (per-lane global addresses)
    const int o_l = l >> 3, fq_l = l & 7;
    const float* wa = (w == 0) ? wzr : (w == 1) ? wzi : (w == 2) ? wrr : wri;
    const float* wsrc = wa + (size_t)(blockIdx.y * 8 + o_l) * NFREQ
                           + blockIdx.x * 32 + fq_l * 4;
    const int ski = w >> 1;                   // Hf ki staged by this wave
    const int sb  = (w & 1) * 4 + (l >> 4);   // local b staged by this lane
    const float2* hsrc = Hf + (size_t)((blockIdx.z * 8 + sb) * 64) * NFREQ
                            + blockIdx.x * 32 + (l & 15) * 2;

    float zre[2][4], zim[2][4], rre[2][4], rim[2][4];
#pragma unroll
    for (int b = 0; b < 2; ++b)
#pragma unroll
        for (int k = 0; k < 4; ++k) {
            zre[b][k] = 0.0f; zim[b][k] = 0.0f;
            rre[b][k] = 0.0f; rim[b][k] = 0.0f;
        }

    // prologue: stage step 0 (i = 0,1) into buf 0
    gld_lds16(wsrc,                       &Wl[0][0][w][0]);
    gld_lds16(wsrc + wstep,               &Wl[0][1][w][0]);
    gld_lds16(hsrc + (size_t)ski * NFREQ, &Hl[0][ski][(w & 1) * 4][0]);
    __syncthreads();   // implicit vmcnt(0) drain

    for (int s = 0; s < 32; ++s) {
        const int buf = s & 1;
        if (s < 31) {                      // stage next step into buf^1
            const int i0 = 2 * (s + 1);
            gld_lds16(wsrc + (size_t)i0 * wstep,         &Wl[buf ^ 1][0][w][0]);
            gld_lds16(wsrc + (size_t)(i0 + 1) * wstep,   &Wl[buf ^ 1][1][w][0]);
            gld_lds16(hsrc + (size_t)(i0 + ski) * NFREQ, &Hl[buf ^ 1][ski][(w & 1) * 4][0]);
        }
#pragma unroll
        for (int ki = 0; ki < 2; ++ki) {
            const float4 vzr = Wl[buf][ki][0][og * 8 + fq];
            const float4 vzi = Wl[buf][ki][1][og * 8 + fq];
            const float4 vrr = Wl[buf][ki][2][og * 8 + fq];
            const float4 vri = Wl[buf][ki][3][og * 8 + fq];
#pragma unroll
            for (int bb = 0; bb < 2; ++bb) {
                const float4 hA = Hl[buf][ki][w * 2 + bb][2 * fq];
                const float4 hB = Hl[buf][ki][w * 2 + bb][2 * fq + 1];
                cmadd4(zre[bb], zim[bb], hA, hB, vzr, vzi);
                cmadd4(rre[bb], rim[bb], hA, hB, vrr, vri);
            }
        }
        __syncthreads();                   // next buf fully written
    }

#pragma unroll
    for (int b = 0; b < 2; ++b) {
        float4* pz = (float4*)(Zf + (size_t)((b0 + b) * 64 + o) * NFREQ + fA);
        float4* pr = (float4*)(Rf + (size_t)((b0 + b) * 64 + o) * NFREQ + fA);
        pz[0] = make_float4(zre[b][0], zim[b][0], zre[b][1], zim[b][1]);
        pz[1] = make_float4(zre[b][2], zim[b][2], zre[b][3], zim[b][3]);
        pr[0] = make_float4(rre[b][0], rim[b][0], rre[b][1], rim[b][1]);
        pr[1] = make_float4(rre[b][2], rim[b][2], rre[b][3], rim[b][3]);
    }
}

__global__ __launch_bounds__(256) void k_pw1(const float2* __restrict__ Hf,
                                             const float* __restrict__ whr,
                                             const float* __restrict__ whi,
                                             float2* __restrict__ Of) {
    __shared__ float4 Wl[2][2][2][64];   // 8 KB
    __shared__ float4 Hl[2][2][8][16];   // 8 KB
    const int t  = threadIdx.x;
    const int l  = t & 63, w = t >> 6;
    const int fq = t & 7,  og = (t >> 3) & 7;
    const int o  = blockIdx.y * 8 + og;
    const int b0 = blockIdx.z * 8 + w * 2;
    const int fA = blockIdx.x * 32 + fq * 4;
    const size_t wstep = (size_t)64 * NFREQ;

    // wave w stages weight (ki=w>>1, arr=w&1) and Hf (ki=w>>1, half=w&1)
    const int o_l = l >> 3, fq_l = l & 7;
    const int ski = w >> 1;
    const float* wa = (w & 1) ? whi : whr;
    const float* wsrc = wa + (size_t)(blockIdx.y * 8 + o_l) * NFREQ
                           + blockIdx.x * 32 + fq_l * 4;
    const int sb  = (w & 1) * 4 + (l >> 4);
    const float2* hsrc = Hf + (size_t)((blockIdx.z * 8 + sb) * 64) * NFREQ
                            + blockIdx.x * 32 + (l & 15) * 2;

    float cre[2][4], cim[2][4];
#pragma unroll
    for (int b = 0; b < 2; ++b)
#pragma unroll
        for (int k = 0; k < 4; ++k) { cre[b][k] = 0.0f; cim[b][k] = 0.0f; }

    gld_lds16(wsrc + (size_t)ski * wstep, &Wl[0][ski][w & 1][0]);
    gld_lds16(hsrc + (size_t)ski * NFREQ, &Hl[0][ski][(w & 1) * 4][0]);
    __syncthreads();

    for (int s = 0; s < 32; ++s) {
        const int buf = s & 1;
        if (s < 31) {
            const int i0 = 2 * (s + 1);
            gld_lds16(wsrc + (size_t)(i0 + ski) * wstep, &Wl[buf ^ 1][ski][w & 1][0]);
            gld_lds16(hsrc + (size_t)(i0 + ski) * NFREQ, &Hl[buf ^ 1][ski][(w & 1) * 4][0]);
        }
#pragma unroll
        for (int ki = 0; ki < 2; ++ki) {
            const float4 vr = Wl[buf][ki][0][og * 8 + fq];
            const float4 vi = Wl[buf][ki][1][og * 8 + fq];
#pragma unroll
            for (int bb = 0; bb < 2; ++bb) {
                const float4 hA = Hl[buf][ki][w * 2 + bb][2 * fq];
                const float4 hB = Hl[buf][ki][w * 2 + bb][2 * fq + 1];
                cmadd4(cre[bb], cim[bb], hA, hB, vr, vi);
            }
        }
        __syncthreads();
    }

#pragma unroll
    for (int b = 0; b < 2; ++b) {
        float4* po = (float4*)(Of + (size_t)((b0 + b) * 64 + o) * NFREQ + fA);
        po[0] = make_float4(cre[b][0], cim[b][0], cre[b][1], cim[b][1]);
        po[1] = make_float4(cre[b][2], cim[b][2], cre[b][3], cim[b][3]);
    }
}

// ---------------- y = h @ Wo + bo, per step --------------------------------
__global__ __launch_bounds__(256) void k_yproj(const float* __restrict__ h,
                                               const float* __restrict__ Wo,
                                               const float* __restrict__ bo,
                                               float* __restrict__ out,
                                               int step) {
    __shared__ float wo[64];
    const int t = threadIdx.x;
    if (t < 64) wo[t] = Wo[t];
    __syncthreads();
    const int b = blockIdx.x >> 4, xg = blockIdx.x & 15;
    const int xx = xg * 4 + (t >> 6), y = t & 63;
    const float* hp = h + (size_t)b * 64 * IMGSZ + xx * 64 + y;
    float acc = bo[0];
#pragma unroll 8
    for (int c = 0; c < 64; ++c) acc += hp[(size_t)c * IMGSZ] * wo[c];
    out[((size_t)b * 20 + step) * IMGSZ + xx * 64 + y] = acc;
}

// ---------------------------------------------------------------------------
extern "C" void kernel_launch(void* const* d_in, const int* in_sizes, int n_in,
                              void* d_out, int out_size, void* d_ws, size_t ws_size,
                              hipStream_t stream) {
    const float* x    = (const float*)d_in[0];
    // d_in[1] = num_time_steps (always 20 per setup_inputs)
    const float* Wi   = (const float*)d_in[2];
    const float* bi   = (const float*)d_in[3];
    const float* Wo   = (const float*)d_in[4];
    const float* bo   = (const float*)d_in[5];
    const float* Wz_r = (const float*)d_in[6];
    const float* Wz_i = (const float*)d_in[7];
    const float* Wr_r = (const float*)d_in[8];
    const float* Wr_i = (const float*)d_in[9];
    const float* Wh_r = (const float*)d_in[10];
    const float* Wh_i = (const float*)d_in[11];

    float* ws = (float*)d_ws;
    float* h = ws;                              // 4,194,304 floats
    float2* B0 = (float2*)(ws + 4194304);       // 2,162,688 float2 each
    float2* B1 = B0 + 2162688;
    float2* B2 = B1 + 2162688;
    float* outp = (float*)d_out;

    k_h0fft<<<NIMG, 64, 0, stream>>>(x, Wi, bi, h, B0);   // h0, Hf -> B0

    for (int t = 0; t < 20; ++t) {
        k_pw2<<<dim3(66, 8, 2), 256, 0, stream>>>(B0, Wz_r, Wz_i, Wr_r, Wr_i,
                                                  B1, B2);  // Zf->B1 Rf->B2
        k_fifft_r<<<NIMG, 64, 0, stream>>>(B2, h, B2);      // RHf -> B2
        k_pw1<<<dim3(66, 8, 2), 256, 0, stream>>>(B2, Wh_r, Wh_i, B0); // Nf->B0
        k_fifft_n<<<NIMG, 64, 0, stream>>>(B0, B1, h, B0);  // h, Hf_next -> B0
        k_yproj<<<256, 256, 0, stream>>>(h, Wo, bo, outp, t);
    }
}